// Round 4
// baseline (613.597 us; speedup 1.0000x reference)
//
#include <hip/hip_runtime.h>

#define CH   16
#define HID  128
#define DIM  64
#define NVOX (4 * DIM * DIM * DIM)

typedef __attribute__((ext_vector_type(8))) short short8;
typedef __attribute__((ext_vector_type(4))) float f32x4;

__device__ __forceinline__ unsigned short f2bf(float f) {
    union { float f; unsigned int u; } c; c.f = f;
    unsigned int u = c.u;
    u += 0x7FFFu + ((u >> 16) & 1u);          // round-nearest-even
    return (unsigned short)(u >> 16);
}

// Swapped-operand MFMA formulation:
//   stage1: H^T = W1^T @ Y^T  (A = weight frag from LDS, B = conv accumulators)
//   stage2: E   = W2^T @ H^T  (B-frag == lane's own stage1 outputs, zero exchange)
// k-slot maps (identical on A and B sides, so the contraction is unchanged):
//   stage1: kappa1(h,g,j) = 16g + 4*(j>>1) + 2h + (j&1)   (feature = 4*chan+op)
//   stage2: kappa2(s,g,j) = 16*(2s + (j>>2)) + 4g + (j&3) (hidden index)
__global__ __launch_bounds__(256, 4) void nca_pass1(
    const float* __restrict__ x,  const float* __restrict__ w1,
    const float* __restrict__ b1, const float* __restrict__ w2,
    const float* __restrict__ b2, const float* __restrict__ ru,
    float* __restrict__ out, float* __restrict__ alpha_new,
    float* __restrict__ pre_life)
{
    __shared__ __align__(16) unsigned short sA1[8192];  // [n][h][g][m][j] 16KB
    __shared__ __align__(16) unsigned short sA2[2048];  // [s][g][m][j]     4KB
    __shared__ __align__(16) float sb1[HID];
    __shared__ __align__(16) float sb2[CH];

    for (int t = threadIdx.x; t < 8192; t += 256) {
        const int j = t & 7, mm = (t >> 3) & 15, gg = (t >> 7) & 3,
                  hh = (t >> 9) & 1, nn = t >> 10;
        const int row = 16 * gg + 4 * (j >> 1) + 2 * hh + (j & 1);  // kappa1
        sA1[t] = f2bf(w1[row * HID + 16 * nn + mm]);
    }
    for (int t = threadIdx.x; t < 2048; t += 256) {
        const int j = t & 7, mm = (t >> 3) & 15, gg = (t >> 7) & 3, ss = t >> 9;
        const int kk = 32 * ss + 16 * (j >> 2) + 4 * gg + (j & 3);  // kappa2
        sA2[t] = f2bf(w2[kk * CH + mm]);
    }
    if (threadIdx.x < HID) sb1[threadIdx.x] = b1[threadIdx.x];
    if (threadIdx.x < CH)  sb2[threadIdx.x] = b2[threadIdx.x];
    __syncthreads();

    const int lane = threadIdx.x & 63;
    const int wid  = threadIdx.x >> 6;
    const int m = lane & 15;
    const int g = lane >> 4;

    // each wave owns one full x-row of 64 voxels (4 MFMA tiles of 16)
    const int row = blockIdx.x * 4 + wid;
    const int hy = row & 63;
    const int dz = (row >> 6) & 63;
    const int bb = row >> 12;
    const int rowvox = row * 64;

    const short8* pA1 = ((const short8*)sA1) + (g * 16 + m);
    const short8* pA2 = ((const short8*)sA2) + (g * 16 + m);

    f32x4 bias1[8];
    #pragma unroll
    for (int n = 0; n < 8; n++)
        bias1[n] = *(const f32x4*)(sb1 + 16 * n + 4 * g);
    const f32x4 bias2 = *(const f32x4*)(sb2 + 4 * g);

    constexpr float A3[3] = {1.0f, 0.0f, -1.0f};
    constexpr float S3[3] = {1.0f, 2.0f, 1.0f};

    for (int t = 0; t < 4; t++) {
        const int wx = 16 * t + m;

        int   xoff[3];
        float okx[3];
        #pragma unroll
        for (int k = 0; k < 3; k++) {
            int xx = wx + k - 1;
            const bool ok = (unsigned)xx < 64u;
            if (xx < 0) xx = 0;
            if (xx > 63) xx = 63;
            xoff[k] = xx * CH + 4 * g;      // clamped addr; value zeroed by okf
            okx[k] = ok ? 1.0f : 0.0f;
        }

        float acc[4][4];                     // [channel c''][op: id,d1,d2,d3]
        #pragma unroll
        for (int c = 0; c < 4; c++)
            #pragma unroll
            for (int o = 0; o < 4; o++) acc[c][o] = 0.0f;
        float pre_max = -1e30f;

        #pragma unroll
        for (int i = 0; i < 3; i++) {
            int zz = dz + i - 1;
            const bool okz = (unsigned)zz < 64u;
            if (zz < 0) zz = 0;
            if (zz > 63) zz = 63;
            #pragma unroll
            for (int j = 0; j < 3; j++) {
                int yy = hy + j - 1;
                const bool oky = (unsigned)yy < 64u;
                if (yy < 0) yy = 0;
                if (yy > 63) yy = 63;
                const float okzy = (okz && oky) ? 1.0f : 0.0f;
                const float* pz =
                    x + (size_t)(((bb * 64 + zz) * 64 + yy) * 64) * CH;
                #pragma unroll
                for (int k = 0; k < 3; k++) {
                    f32x4 v = *(const f32x4*)(pz + xoff[k]);
                    const float okf = okzy * okx[k];
                    v *= okf;                // masked; zeros safe for >0.1 test
                    const float d1 = A3[i] * S3[j] * S3[k] * (1.0f / 32.0f);
                    const float d2 = A3[j] * S3[i] * S3[k] * (1.0f / 32.0f);
                    const float d3 = A3[k] * S3[j] * S3[i] * (1.0f / 32.0f);
                    #pragma unroll
                    for (int c = 0; c < 4; c++) {
                        acc[c][1] = fmaf(d1, v[c], acc[c][1]);
                        acc[c][2] = fmaf(d2, v[c], acc[c][2]);
                        acc[c][3] = fmaf(d3, v[c], acc[c][3]);
                    }
                    if (i == 1 && j == 1 && k == 1) {
                        acc[0][0] = v[0]; acc[1][0] = v[1];
                        acc[2][0] = v[2]; acc[3][0] = v[3];
                    }
                    pre_max = fmaxf(pre_max, v[3]);  // alpha (=ch3) on g==0
                }
            }
        }

        short8 a0, a1;                       // B-frags: Y[m][kappa1(h,g,j)]
        #pragma unroll
        for (int c = 0; c < 4; c++) {
            a0[2 * c + 0] = (short)f2bf(acc[c][0]);
            a0[2 * c + 1] = (short)f2bf(acc[c][1]);
            a1[2 * c + 0] = (short)f2bf(acc[c][2]);
            a1[2 * c + 1] = (short)f2bf(acc[c][3]);
        }

        // stage 1: 8 n-tiles, lane ends with hs[n][r] = H[m][16n+4g+r]
        f32x4 hs[8];
        #pragma unroll
        for (int n = 0; n < 8; n++) {
            f32x4 h = bias1[n];
            h = __builtin_amdgcn_mfma_f32_16x16x32_bf16(pA1[(2 * n + 0) * 64], a0, h, 0, 0, 0);
            h = __builtin_amdgcn_mfma_f32_16x16x32_bf16(pA1[(2 * n + 1) * 64], a1, h, 0, 0, 0);
            #pragma unroll
            for (int r = 0; r < 4; r++) hs[n][r] = fmaxf(h[r], 0.0f);
        }

        // stage 2: B-frag is the lane's own hs values under kappa2
        f32x4 e = bias2;
        #pragma unroll
        for (int s = 0; s < 4; s++) {
            short8 bf;
            #pragma unroll
            for (int r = 0; r < 4; r++) {
                bf[r]     = (short)f2bf(hs[2 * s + 0][r]);
                bf[4 + r] = (short)f2bf(hs[2 * s + 1][r]);
            }
            e = __builtin_amdgcn_mfma_f32_16x16x32_bf16(pA2[s * 64], bf, e, 0, 0, 0);
        }

        // epilogue: lane (m,g) owns voxel m, channels 4g..4g+3
        const int vox = rowvox + wx;
        const float mask = (ru[vox] <= 0.5f) ? 1.0f : 0.0f;
        f32x4 xn;
        #pragma unroll
        for (int r = 0; r < 4; r++) xn[r] = fmaf(e[r], mask, acc[r][0]);
        *(f32x4*)(out + (size_t)vox * CH + 4 * g) = xn;
        if (g == 0) {
            alpha_new[vox] = xn[3];
            pre_life[vox]  = (pre_max > 0.1f) ? 1.0f : 0.0f;
        }
    }
}

__global__ __launch_bounds__(256) void nca_pass2(
    const float* __restrict__ alpha_new, const float* __restrict__ pre_life,
    float* __restrict__ out)
{
    const int idx = blockIdx.x * 256 + threadIdx.x;
    const int wx = idx & 63;
    const int hy = (idx >> 6) & 63;
    const int dz = (idx >> 12) & 63;

    float m = -1e30f;
    #pragma unroll
    for (int i = 0; i < 3; i++) {
        const int zz = dz + i - 1;
        if ((unsigned)zz >= 64u) continue;
        #pragma unroll
        for (int j = 0; j < 3; j++) {
            const int yy = hy + j - 1;
            if ((unsigned)yy >= 64u) continue;
            #pragma unroll
            for (int k = 0; k < 3; k++) {
                const int xx = wx + k - 1;
                if ((unsigned)xx >= 64u) continue;
                m = fmaxf(m, alpha_new[idx + (i - 1) * 4096 + (j - 1) * 64 + (k - 1)]);
            }
        }
    }
    const float life = (m > 0.1f && pre_life[idx] > 0.5f) ? 1.0f : 0.0f;

    float4* p = (float4*)(out + (size_t)idx * CH);
    #pragma unroll
    for (int q = 0; q < 4; q++) {
        float4 v = p[q];
        v.x *= life; v.y *= life; v.z *= life; v.w *= life;
        p[q] = v;
    }
}

extern "C" void kernel_launch(void* const* d_in, const int* in_sizes, int n_in,
                              void* d_out, int out_size, void* d_ws, size_t ws_size,
                              hipStream_t stream) {
    const float* x  = (const float*)d_in[0];
    const float* w1 = (const float*)d_in[1];
    const float* b1 = (const float*)d_in[2];
    const float* w2 = (const float*)d_in[3];
    const float* b2 = (const float*)d_in[4];
    const float* ru = (const float*)d_in[5];
    float* out = (float*)d_out;

    float* alpha_new = (float*)d_ws;
    float* pre_life  = alpha_new + NVOX;

    // 16384 x-rows, 4 rows (waves) per block
    hipLaunchKernelGGL(nca_pass1, dim3(4096), dim3(256), 0, stream,
                       x, w1, b1, w2, b2, ru, out, alpha_new, pre_life);
    hipLaunchKernelGGL(nca_pass2, dim3(NVOX / 256), dim3(256), 0, stream,
                       alpha_new, pre_life, out);
}

// Round 5
// 267.277 us; speedup vs baseline: 2.2957x; 2.2957x over previous
//
#include <hip/hip_runtime.h>

#define CH   16
#define HID  128
#define DIM  64
#define NVOX (4 * DIM * DIM * DIM)

typedef __attribute__((ext_vector_type(8))) short short8;
typedef __attribute__((ext_vector_type(4))) float f32x4;

__device__ __forceinline__ unsigned short f2bf(float f) {
    union { float f; unsigned int u; } c; c.f = f;
    unsigned int u = c.u;
    u += 0x7FFFu + ((u >> 16) & 1u);          // round-nearest-even
    return (unsigned short)(u >> 16);
}

// Swapped-operand MFMA formulation:
//   stage1: H^T = W1^T @ Y^T  (A = weight frag from LDS, B = conv accumulators)
//   stage2: E   = W2^T @ H^T  (B-frag == lane's own stage1 outputs, zero exchange)
// k-slot maps (identical on A and B sides, so the contraction is unchanged):
//   stage1: kappa1(h,g,j) = 16g + 4*(j>>1) + 2h + (j&1)   (feature = 4*chan+op)
//   stage2: kappa2(s,g,j) = 16*(2s + (j>>2)) + 4g + (j&3) (hidden index)
// NOTE: no min-waves clamp -- R4's (256,4) forced VGPR=64 and spilled to
// scratch (WRITE_SIZE 75->709 MB). Let the allocator take ~100 VGPRs.
__global__ __launch_bounds__(256) void nca_pass1(
    const float* __restrict__ x,  const float* __restrict__ w1,
    const float* __restrict__ b1, const float* __restrict__ w2,
    const float* __restrict__ b2, const float* __restrict__ ru,
    float* __restrict__ out, float* __restrict__ alpha_new,
    float* __restrict__ pre_life)
{
    __shared__ __align__(16) unsigned short sA1[8192];  // [n][h][g][m][j] 16KB
    __shared__ __align__(16) unsigned short sA2[2048];  // [s][g][m][j]     4KB
    __shared__ __align__(16) float sb1[HID];
    __shared__ __align__(16) float sb2[CH];

    for (int t = threadIdx.x; t < 8192; t += 256) {
        const int j = t & 7, mm = (t >> 3) & 15, gg = (t >> 7) & 3,
                  hh = (t >> 9) & 1, nn = t >> 10;
        const int row = 16 * gg + 4 * (j >> 1) + 2 * hh + (j & 1);  // kappa1
        sA1[t] = f2bf(w1[row * HID + 16 * nn + mm]);
    }
    for (int t = threadIdx.x; t < 2048; t += 256) {
        const int j = t & 7, mm = (t >> 3) & 15, gg = (t >> 7) & 3, ss = t >> 9;
        const int kk = 32 * ss + 16 * (j >> 2) + 4 * gg + (j & 3);  // kappa2
        sA2[t] = f2bf(w2[kk * CH + mm]);
    }
    if (threadIdx.x < HID) sb1[threadIdx.x] = b1[threadIdx.x];
    if (threadIdx.x < CH)  sb2[threadIdx.x] = b2[threadIdx.x];
    __syncthreads();

    const int lane = threadIdx.x & 63;
    const int wid  = threadIdx.x >> 6;
    const int m = lane & 15;
    const int g = lane >> 4;

    // each wave owns one full x-row of 64 voxels (4 MFMA tiles of 16)
    const int row = blockIdx.x * 4 + wid;
    const int hy = row & 63;
    const int dz = (row >> 6) & 63;
    const int bb = row >> 12;
    const int rowvox = row * 64;

    const short8* pA1 = ((const short8*)sA1) + (g * 16 + m);
    const short8* pA2 = ((const short8*)sA2) + (g * 16 + m);
    const float*  pb1 = sb1 + 4 * g;
    const float*  pb2 = sb2 + 4 * g;

    constexpr float A3[3] = {1.0f, 0.0f, -1.0f};
    constexpr float S3[3] = {1.0f, 2.0f, 1.0f};

    for (int t = 0; t < 4; t++) {
        const int wx = 16 * t + m;

        int   xoff[3];
        float okx[3];
        #pragma unroll
        for (int k = 0; k < 3; k++) {
            int xx = wx + k - 1;
            const bool ok = (unsigned)xx < 64u;
            if (xx < 0) xx = 0;
            if (xx > 63) xx = 63;
            xoff[k] = xx * CH + 4 * g;      // clamped addr; value zeroed by okf
            okx[k] = ok ? 1.0f : 0.0f;
        }

        float acc[4][4];                     // [channel c''][op: id,d1,d2,d3]
        #pragma unroll
        for (int c = 0; c < 4; c++)
            #pragma unroll
            for (int o = 0; o < 4; o++) acc[c][o] = 0.0f;
        float pre_max = -1e30f;

        #pragma unroll
        for (int i = 0; i < 3; i++) {
            int zz = dz + i - 1;
            const bool okz = (unsigned)zz < 64u;
            if (zz < 0) zz = 0;
            if (zz > 63) zz = 63;
            #pragma unroll
            for (int j = 0; j < 3; j++) {
                int yy = hy + j - 1;
                const bool oky = (unsigned)yy < 64u;
                if (yy < 0) yy = 0;
                if (yy > 63) yy = 63;
                const float okzy = (okz && oky) ? 1.0f : 0.0f;
                const float* pz =
                    x + (size_t)(((bb * 64 + zz) * 64 + yy) * 64) * CH;
                #pragma unroll
                for (int k = 0; k < 3; k++) {
                    f32x4 v = *(const f32x4*)(pz + xoff[k]);
                    const float okf = okzy * okx[k];
                    v *= okf;                // masked; zeros safe for >0.1 test
                    const float d1 = A3[i] * S3[j] * S3[k] * (1.0f / 32.0f);
                    const float d2 = A3[j] * S3[i] * S3[k] * (1.0f / 32.0f);
                    const float d3 = A3[k] * S3[j] * S3[i] * (1.0f / 32.0f);
                    #pragma unroll
                    for (int c = 0; c < 4; c++) {
                        acc[c][1] = fmaf(d1, v[c], acc[c][1]);
                        acc[c][2] = fmaf(d2, v[c], acc[c][2]);
                        acc[c][3] = fmaf(d3, v[c], acc[c][3]);
                    }
                    if (i == 1 && j == 1 && k == 1) {
                        acc[0][0] = v[0]; acc[1][0] = v[1];
                        acc[2][0] = v[2]; acc[3][0] = v[3];
                    }
                    pre_max = fmaxf(pre_max, v[3]);  // alpha (=ch3) on g==0
                }
            }
        }

        short8 a0, a1;                       // B-frags: Y[m][kappa1(h,g,j)]
        f32x4 center;
        #pragma unroll
        for (int c = 0; c < 4; c++) {
            a0[2 * c + 0] = (short)f2bf(acc[c][0]);
            a0[2 * c + 1] = (short)f2bf(acc[c][1]);
            a1[2 * c + 0] = (short)f2bf(acc[c][2]);
            a1[2 * c + 1] = (short)f2bf(acc[c][3]);
            center[c] = acc[c][0];
        }

        // stage 1: 8 n-tiles; pack relu(H) to bf16 immediately (16 regs, not 32)
        // stage2 B-frag layout: pbf[s][j]: j<4 -> hs[2s][j], j>=4 -> hs[2s+1][j-4]
        short8 pbf[4];
        #pragma unroll
        for (int n = 0; n < 8; n++) {
            f32x4 h = *(const f32x4*)(pb1 + 16 * n);   // broadcast LDS read
            h = __builtin_amdgcn_mfma_f32_16x16x32_bf16(pA1[(2 * n + 0) * 64], a0, h, 0, 0, 0);
            h = __builtin_amdgcn_mfma_f32_16x16x32_bf16(pA1[(2 * n + 1) * 64], a1, h, 0, 0, 0);
            #pragma unroll
            for (int r = 0; r < 4; r++)
                pbf[n >> 1][((n & 1) << 2) + r] = (short)f2bf(fmaxf(h[r], 0.0f));
        }

        // stage 2: B-frag is the lane's own packed stage-1 outputs
        f32x4 e = *(const f32x4*)pb2;
        #pragma unroll
        for (int s = 0; s < 4; s++)
            e = __builtin_amdgcn_mfma_f32_16x16x32_bf16(pA2[s * 64], pbf[s], e, 0, 0, 0);

        // epilogue: lane (m,g) owns voxel m, channels 4g..4g+3
        const int vox = rowvox + wx;
        const float mask = (ru[vox] <= 0.5f) ? 1.0f : 0.0f;
        f32x4 xn;
        #pragma unroll
        for (int r = 0; r < 4; r++) xn[r] = fmaf(e[r], mask, center[r]);
        *(f32x4*)(out + (size_t)vox * CH + 4 * g) = xn;
        if (g == 0) {
            alpha_new[vox] = xn[3];
            pre_life[vox]  = (pre_max > 0.1f) ? 1.0f : 0.0f;
        }
    }
}

__global__ __launch_bounds__(256) void nca_pass2(
    const float* __restrict__ alpha_new, const float* __restrict__ pre_life,
    float* __restrict__ out)
{
    const int idx = blockIdx.x * 256 + threadIdx.x;
    const int wx = idx & 63;
    const int hy = (idx >> 6) & 63;
    const int dz = (idx >> 12) & 63;

    float m = -1e30f;
    #pragma unroll
    for (int i = 0; i < 3; i++) {
        const int zz = dz + i - 1;
        if ((unsigned)zz >= 64u) continue;
        #pragma unroll
        for (int j = 0; j < 3; j++) {
            const int yy = hy + j - 1;
            if ((unsigned)yy >= 64u) continue;
            #pragma unroll
            for (int k = 0; k < 3; k++) {
                const int xx = wx + k - 1;
                if ((unsigned)xx >= 64u) continue;
                m = fmaxf(m, alpha_new[idx + (i - 1) * 4096 + (j - 1) * 64 + (k - 1)]);
            }
        }
    }
    const float life = (m > 0.1f && pre_life[idx] > 0.5f) ? 1.0f : 0.0f;

    float4* p = (float4*)(out + (size_t)idx * CH);
    #pragma unroll
    for (int q = 0; q < 4; q++) {
        float4 v = p[q];
        v.x *= life; v.y *= life; v.z *= life; v.w *= life;
        p[q] = v;
    }
}

extern "C" void kernel_launch(void* const* d_in, const int* in_sizes, int n_in,
                              void* d_out, int out_size, void* d_ws, size_t ws_size,
                              hipStream_t stream) {
    const float* x  = (const float*)d_in[0];
    const float* w1 = (const float*)d_in[1];
    const float* b1 = (const float*)d_in[2];
    const float* w2 = (const float*)d_in[3];
    const float* b2 = (const float*)d_in[4];
    const float* ru = (const float*)d_in[5];
    float* out = (float*)d_out;

    float* alpha_new = (float*)d_ws;
    float* pre_life  = alpha_new + NVOX;

    // 16384 x-rows, 4 rows (waves) per block
    hipLaunchKernelGGL(nca_pass1, dim3(4096), dim3(256), 0, stream,
                       x, w1, b1, w2, b2, ru, out, alpha_new, pre_life);
    hipLaunchKernelGGL(nca_pass2, dim3(NVOX / 256), dim3(256), 0, stream,
                       alpha_new, pre_life, out);
}